// Round 9
// baseline (391.339 us; speedup 1.0000x reference)
//
#include <hip/hip_runtime.h>
#include <hip/hip_bf16.h>

// Dims (fixed for this problem)
#define BB 2
#define LL 1024
#define DMODEL 1024
#define DINNER 2048
#define DSTATE 16
#define DCONV 4
#define MM (BB * LL)          // 2048
#define N_XZ 4096
#define N_SSM 2080
#define N_SSM_PAD 2176        // 17 * 128
#define CCH 32                // chunks over L
#define LCH 32                // chunk length (CCH*LCH == LL)

typedef __hip_bfloat16 bf16;
typedef short bf16x8 __attribute__((ext_vector_type(8)));
typedef float f32x4 __attribute__((ext_vector_type(4)));

// ---------------- async global -> LDS, 16B per lane ----------------
__device__ __forceinline__ void load16_lds(const bf16* g, bf16* l) {
    __builtin_amdgcn_global_load_lds(
        (const __attribute__((address_space(1))) void*)g,
        (__attribute__((address_space(3))) void*)l,
        16, 0, 0);
}

// ---------------- fp32 -> bf16 straight cast ----------------
__global__ void cvt_kernel(const float* __restrict__ in, bf16* __restrict__ out, int n) {
    int i = blockIdx.x * blockDim.x + threadIdx.x;
    if (i < n) out[i] = __float2bfloat16(in[i]);
}

// ---------------- transpose + cast: W fp32 [K,N] -> Wt bf16 [N,K] ----------------
__global__ void transpose_cvt_kernel(const float* __restrict__ in, bf16* __restrict__ out,
                                     int K, int N) {
    __shared__ float tile[32][33];
    const int nb = blockIdx.x * 32, kb = blockIdx.y * 32;
    const int tx = threadIdx.x & 31;
    const int ty = threadIdx.x >> 5;
    #pragma unroll
    for (int i = 0; i < 32; i += 8) {
        int k = kb + ty + i, n = nb + tx;
        tile[ty + i][tx] = (k < K && n < N) ? in[(size_t)k * N + n] : 0.f;
    }
    __syncthreads();
    #pragma unroll
    for (int i = 0; i < 32; i += 8) {
        int n = nb + ty + i, k = kb + tx;
        if (n < N && k < K) out[(size_t)n * K + k] = __float2bfloat16(tile[tx][ty + i]);
    }
}

// ---------------- MFMA GEMM v3: 128x128 tile, glds dbuf, swizzled LDS --------------
// C[M,N] = A[M,K](bf16) @ Wt[N,K](bf16)^T
// EPI: 0 = bf16 store (col<N guard), 1 = +bias softplus f32, 2 = f32 (atomic if KSPLIT>1),
//      3 = cols<32 -> f32 BC sideband, cols in [32,N) -> bf16
#define TM 128
#define TN 128
#define TK 32
template<int EPI, int KSPLIT = 1>
__global__ __launch_bounds__(256) void mfma_gemm(
    const bf16* __restrict__ A, int lda,
    const bf16* __restrict__ Wt, int ldw,
    float* __restrict__ Cf, bf16* __restrict__ Cb, int ldc,
    const float* __restrict__ bias,
    int N, int K)
{
    __shared__ __align__(16) bf16 As[2][TM * TK];   // 8 KB each
    __shared__ __align__(16) bf16 Bs[2][TN * TK];   // 8 KB each (32 KB total)
    const int tid = threadIdx.x;
    const int wave = tid >> 6, lane = tid & 63;
    const int wm = (wave >> 1) * 64, wn = (wave & 1) * 64;
    const int m0 = blockIdx.y * TM, n0 = blockIdx.x * TN;
    const int lm = lane & 15, kq = lane >> 4;

    // staging: lane covers row srow (of a 16-row wave slab), fetches swizzled chunk cg
    const int srow = lane >> 2;
    const int cg = ((lane & 3) - ((srow >> 1) & 3)) & 3;
    const bf16* gA = A + (size_t)(m0 + wave * 16 + srow) * lda + cg * 8;
    const bf16* gB = Wt + (size_t)(n0 + wave * 16 + srow) * ldw + cg * 8;
    const int ldsOff = (wave * 16) * TK;   // wave-uniform glds dest

    // fragment-read slot (swizzle inverse): slot = (kq + (row>>1)) & 3
    const int soff = ((kq + ((lm >> 1) & 3)) & 3) * 8;

    const int Kc = K / KSPLIT;
    const int kbeg = (KSPLIT > 1) ? blockIdx.z * Kc : 0;
    const int NK = Kc / TK;   // even for all our shapes

    f32x4 acc[4][4] = {};

    auto stage = [&](int buf, int it) {
        const int k0 = kbeg + it * TK;
        load16_lds(gA + k0, &As[buf][ldsOff]);
        load16_lds(gA + (size_t)64 * lda + k0, &As[buf][ldsOff + 64 * TK]);
        load16_lds(gB + k0, &Bs[buf][ldsOff]);
        load16_lds(gB + (size_t)64 * ldw + k0, &Bs[buf][ldsOff + 64 * TK]);
    };
    auto compute = [&](int buf) {
        bf16x8 af[4], bfr[4];
        #pragma unroll
        for (int i = 0; i < 4; ++i)
            af[i] = *(const bf16x8*)(&As[buf][(wm + i * 16 + lm) * TK + soff]);
        #pragma unroll
        for (int j = 0; j < 4; ++j)
            bfr[j] = *(const bf16x8*)(&Bs[buf][(wn + j * 16 + lm) * TK + soff]);
        #pragma unroll
        for (int i = 0; i < 4; ++i)
            #pragma unroll
            for (int j = 0; j < 4; ++j)
                acc[i][j] = __builtin_amdgcn_mfma_f32_16x16x32_bf16(af[i], bfr[j], acc[i][j], 0, 0, 0);
    };

    stage(0, 0);
    for (int it = 0; it < NK; it += 2) {
        stage(1, it + 1);
        __builtin_amdgcn_s_waitcnt(0x0F74);   // vmcnt(4): buf0 complete, buf1 in flight
        __builtin_amdgcn_s_barrier();
        compute(0);
        __builtin_amdgcn_s_barrier();
        if (it + 2 < NK) {
            stage(0, it + 2);
            __builtin_amdgcn_s_waitcnt(0x0F74);  // buf1 complete, buf0 in flight
        } else {
            __builtin_amdgcn_s_waitcnt(0x0F70);  // vmcnt(0)
        }
        __builtin_amdgcn_s_barrier();
        compute(1);
        __builtin_amdgcn_s_barrier();
    }

    // D layout: col = lane&15, row = (lane>>4)*4 + r (m89-verified)
    #pragma unroll
    for (int i = 0; i < 4; ++i) {
        #pragma unroll
        for (int j = 0; j < 4; ++j) {
            int gcol = n0 + wn + j * 16 + lm;
            if ((EPI == 0 || EPI == 3) && gcol >= N) continue;
            #pragma unroll
            for (int r = 0; r < 4; ++r) {
                int grow = m0 + wm + i * 16 + kq * 4 + r;
                float v = acc[i][j][r];
                if (EPI == 1) {
                    v += bias[gcol];
                    v = (v > 20.f) ? v : log1pf(__expf(v));
                    Cf[(size_t)grow * ldc + gcol] = v;
                } else if (EPI == 2) {
                    if (KSPLIT > 1) atomicAdd(&Cf[(size_t)grow * ldc + gcol], v);
                    else            Cf[(size_t)grow * ldc + gcol] = v;
                } else if (EPI == 3) {
                    if (gcol < 32) Cf[(size_t)grow * 32 + gcol] = v;     // BC f32 sideband
                    else           Cb[(size_t)grow * ldc + gcol] = __float2bfloat16(v);
                } else {
                    Cb[(size_t)grow * ldc + gcol] = __float2bfloat16(v);
                }
            }
        }
    }
}

// ---------------- depthwise causal conv (k=4) + bias + SiLU (bf16 io) ----------------
__global__ void conv_silu_kernel(const bf16* __restrict__ xz,
                                 const float* __restrict__ conv_w,
                                 const float* __restrict__ conv_b,
                                 bf16* __restrict__ u)
{
    int idx = blockIdx.x * blockDim.x + threadIdx.x;
    if (idx >= BB * LL * DINNER) return;
    int d = idx & (DINNER - 1);
    int l = (idx >> 11) & (LL - 1);
    int b = idx >> 21;
    float acc = conv_b[d];
    #pragma unroll
    for (int j = 0; j < DCONV; ++j) {
        int ll = l - (DCONV - 1) + j;
        if (ll >= 0) {
            float xv = (float)xz[((size_t)(b * LL + ll)) * N_XZ + d];
            acc = fmaf(conv_w[d * DCONV + j], xv, acc);
        }
    }
    u[idx] = __float2bfloat16(acc / (1.f + __expf(-acc)));
}

// ---------------- scan phase A: lane per (b,d,chunk), h[16] in regs ----------------
__global__ __launch_bounds__(256) void scan_phase_a(
    const float* __restrict__ dt, const bf16* __restrict__ u,
    const float* __restrict__ BC,    // (B,L,32) f32: B=[0:16), C=[16:32)
    const float* __restrict__ A_log,
    float* __restrict__ chunkP, float* __restrict__ chunkH)
{
    const int d = blockIdx.x * 256 + threadIdx.x;
    const int c = blockIdx.y, b = blockIdx.z;
    const int l0 = c * LCH;

    float A[DSTATE];
    {
        const f32x4* ap = (const f32x4*)(A_log + d * DSTATE);
        #pragma unroll
        for (int q = 0; q < 4; ++q) {
            f32x4 v = ap[q];
            #pragma unroll
            for (int r = 0; r < 4; ++r) A[q * 4 + r] = -__expf(v[r]);
        }
    }
    float h[DSTATE];
    #pragma unroll
    for (int n = 0; n < DSTATE; ++n) h[n] = 0.f;
    float sdt = 0.f;

    const float* dtp = dt + ((size_t)b * LL + l0) * DINNER + d;
    const bf16* up = u + ((size_t)b * LL + l0) * DINNER + d;
    const float* bcp = BC + ((size_t)b * LL + l0) * 32;

    #pragma unroll 2
    for (int i = 0; i < LCH; ++i) {
        float dtv = *dtp;
        float uv  = (float)*up;
        float du  = dtv * uv;
        f32x4 Bv[4];
        #pragma unroll
        for (int q = 0; q < 4; ++q) Bv[q] = *(const f32x4*)(bcp + q * 4);
        #pragma unroll
        for (int n = 0; n < DSTATE; ++n) {
            float a = __expf(dtv * A[n]);
            h[n] = fmaf(a, h[n], du * Bv[n >> 2][n & 3]);
        }
        sdt += dtv;
        dtp += DINNER; up += DINNER; bcp += 32;
    }

    size_t idx = (((size_t)b * CCH + c) * DINNER + d) * DSTATE;
    #pragma unroll
    for (int q = 0; q < 4; ++q) {
        f32x4 pv, hv;
        #pragma unroll
        for (int r = 0; r < 4; ++r) { pv[r] = __expf(A[q * 4 + r] * sdt); hv[r] = h[q * 4 + r]; }
        *(f32x4*)(chunkP + idx + q * 4) = pv;
        *(f32x4*)(chunkH + idx + q * 4) = hv;
    }
}

// ---------------- scan phase P: exclusive prefix over chunks, in place on chunkH ----
__global__ __launch_bounds__(256) void scan_phase_p(
    const float* __restrict__ chunkP, float* __restrict__ chunkH)
{
    int gid = blockIdx.x * 256 + threadIdx.x;   // over B*DINNER*DSTATE = 65536
    int n = gid & 15;
    int d = (gid >> 4) & (DINNER - 1);
    int b = gid >> 15;
    const size_t stride = (size_t)DINNER * DSTATE;
    size_t idx = ((size_t)b * CCH * DINNER + d) * DSTATE + n;
    float H = 0.f;
    for (int c = 0; c < CCH; ++c) {
        float P  = chunkP[idx];
        float hl = chunkH[idx];
        chunkH[idx] = H;           // exclusive prefix
        H = fmaf(P, H, hl);
        idx += stride;
    }
}

// ---------------- scan phase B: lane per (b,d,chunk); gated y over u --------
__global__ __launch_bounds__(256) void scan_phase_b(
    const float* __restrict__ dt, bf16* __restrict__ u,
    const float* __restrict__ BC, const bf16* __restrict__ xz,
    const float* __restrict__ A_log, const float* __restrict__ Dp,
    const float* __restrict__ chunkH)
{
    const int d = blockIdx.x * 256 + threadIdx.x;
    const int c = blockIdx.y, b = blockIdx.z;
    const int l0 = c * LCH;

    float A[DSTATE];
    {
        const f32x4* ap = (const f32x4*)(A_log + d * DSTATE);
        #pragma unroll
        for (int q = 0; q < 4; ++q) {
            f32x4 v = ap[q];
            #pragma unroll
            for (int r = 0; r < 4; ++r) A[q * 4 + r] = -__expf(v[r]);
        }
    }
    const float Dd = Dp[d];
    float h[DSTATE];
    {
        size_t idx = (((size_t)b * CCH + c) * DINNER + d) * DSTATE;
        #pragma unroll
        for (int q = 0; q < 4; ++q) {
            f32x4 v = *(const f32x4*)(chunkH + idx + q * 4);
            #pragma unroll
            for (int r = 0; r < 4; ++r) h[q * 4 + r] = v[r];
        }
    }

    const float* dtp = dt + ((size_t)b * LL + l0) * DINNER + d;
    bf16* up = u + ((size_t)b * LL + l0) * DINNER + d;
    const float* bcp = BC + ((size_t)b * LL + l0) * 32;
    const bf16* zp = xz + ((size_t)b * LL + l0) * N_XZ + DINNER + d;

    #pragma unroll 2
    for (int i = 0; i < LCH; ++i) {
        float dtv = *dtp;
        float uv  = (float)*up;
        float du  = dtv * uv;
        f32x4 Bv[4], Cv[4];
        #pragma unroll
        for (int q = 0; q < 4; ++q) {
            Bv[q] = *(const f32x4*)(bcp + q * 4);
            Cv[q] = *(const f32x4*)(bcp + 16 + q * 4);
        }
        float acc = 0.f;
        #pragma unroll
        for (int n = 0; n < DSTATE; ++n) {
            float a = __expf(dtv * A[n]);
            h[n] = fmaf(a, h[n], du * Bv[n >> 2][n & 3]);
            acc = fmaf(h[n], Cv[n >> 2][n & 3], acc);
        }
        float zv = (float)*zp;
        acc = fmaf(Dd, uv, acc);
        acc *= zv / (1.f + __expf(-zv));
        *up = __float2bfloat16(acc);
        dtp += DINNER; up += DINNER; bcp += 32; zp += N_XZ;
    }
}

extern "C" void kernel_launch(void* const* d_in, const int* in_sizes, int n_in,
                              void* d_out, int out_size, void* d_ws, size_t ws_size,
                              hipStream_t stream) {
    const float* x         = (const float*)d_in[0];
    const float* in_proj_w = (const float*)d_in[1];
    const float* conv_w    = (const float*)d_in[2];
    const float* conv_b    = (const float*)d_in[3];
    const float* x_proj_w  = (const float*)d_in[4];
    const float* dt_proj_w = (const float*)d_in[5];
    const float* dt_proj_b = (const float*)d_in[6];
    const float* A_log     = (const float*)d_in[7];
    const float* Dp        = (const float*)d_in[8];
    const float* out_proj_w= (const float*)d_in[9];
    float* out = (float*)d_out;

    // workspace layout (~80.7 MB); xbf aliases dt; chunkP/H alias Wt1/Wt2
    char* p = (char*)d_ws;
    float* dt   = (float*)p;                          p += (size_t)MM * DINNER * 4;
    bf16*  xbf  = (bf16*)dt;
    bf16*  xz   = (bf16*)p;                           p += (size_t)MM * N_XZ * 2;
    bf16*  u    = (bf16*)p;                           p += (size_t)MM * DINNER * 2;
    bf16*  ssm  = (bf16*)p;                           p += (size_t)MM * N_SSM * 2;
    bf16*  Wt1  = (bf16*)p;                           p += (size_t)N_XZ * DMODEL * 2;      // 8 MB
    bf16*  Wt2  = (bf16*)p;                           p += (size_t)N_SSM_PAD * DINNER * 2; // 8.9 MB
    bf16*  Wt3  = (bf16*)p;                           p += (size_t)DINNER * DINNER * 2;
    bf16*  Wt4  = (bf16*)p;                           p += (size_t)DMODEL * DINNER * 2;
    float* BC   = (float*)p;                          p += (size_t)MM * 32 * 4;            // 256 KB
    float* chunkP = (float*)Wt1;   // B*CCH*DINNER*16 f32 = 8 MB exactly
    float* chunkH = (float*)Wt2;   // 8 MB of Wt2's 8.9

    // 0) converts / transposes
    {
        int n = MM * DMODEL;
        cvt_kernel<<<(n + 255) / 256, 256, 0, stream>>>(x, xbf, n);
        transpose_cvt_kernel<<<dim3(N_XZ / 32, DMODEL / 32), 256, 0, stream>>>(in_proj_w, Wt1, DMODEL, N_XZ);
        transpose_cvt_kernel<<<dim3((N_SSM + 31) / 32, DINNER / 32), 256, 0, stream>>>(x_proj_w, Wt2, DINNER, N_SSM);
        transpose_cvt_kernel<<<dim3(DINNER / 32, DINNER / 32), 256, 0, stream>>>(dt_proj_w, Wt3, DINNER, DINNER);
        transpose_cvt_kernel<<<dim3(DMODEL / 32, DINNER / 32), 256, 0, stream>>>(out_proj_w, Wt4, DINNER, DMODEL);
    }
    // 1) xz = xbf @ W1   (2048 x 4096, K=1024), bf16
    mfma_gemm<0><<<dim3(N_XZ / TN, MM / TM), 256, 0, stream>>>(
        xbf, DMODEL, Wt1, DMODEL, nullptr, xz, N_XZ, nullptr, N_XZ, DMODEL);
    // 2) u = silu(conv(x_inner)+b)
    {
        int n = BB * LL * DINNER;
        conv_silu_kernel<<<(n + 255) / 256, 256, 0, stream>>>(xz, conv_w, conv_b, u);
    }
    // 3) ssm = u @ W2    (2048 x 2080, K=2048); cols<32 -> BC f32, rest bf16
    mfma_gemm<3><<<dim3(N_SSM_PAD / TN, MM / TM), 256, 0, stream>>>(
        u, DINNER, Wt2, DINNER, BC, ssm, N_SSM, nullptr, N_SSM, DINNER);
    // 4) dt = softplus(ssm[:,32:] @ W3 + b)  (2048 x 2048, K=2048), fp32
    mfma_gemm<1><<<dim3(DINNER / TN, MM / TM), 256, 0, stream>>>(
        ssm + 2 * DSTATE, N_SSM, Wt3, DINNER, dt, nullptr, DINNER, dt_proj_b, DINNER, DINNER);
    // 5) chunked selective scan: A (local), P (prefix), B (apply; y over u)
    scan_phase_a<<<dim3(DINNER / 256, CCH, BB), 256, 0, stream>>>(dt, u, BC, A_log, chunkP, chunkH);
    scan_phase_p<<<dim3(BB * DINNER * DSTATE / 256), 256, 0, stream>>>(chunkP, chunkH);
    scan_phase_b<<<dim3(DINNER / 256, CCH, BB), 256, 0, stream>>>(dt, u, BC, xz, A_log, Dp, chunkH);
    // 6) out = y @ W4    (2048 x 1024, K=2048), fp32, split-K=2 with atomic accumulate
    hipMemsetAsync(out, 0, (size_t)out_size * sizeof(float), stream);
    mfma_gemm<2, 2><<<dim3(DMODEL / TN, MM / TM, 2), 256, 0, stream>>>(
        u, DINNER, Wt4, DINNER, out, nullptr, DMODEL, nullptr, DMODEL, DINNER);
}

// Round 10
// 374.702 us; speedup vs baseline: 1.0444x; 1.0444x over previous
//
#include <hip/hip_runtime.h>
#include <hip/hip_bf16.h>

// Dims (fixed for this problem)
#define BB 2
#define LL 1024
#define DMODEL 1024
#define DINNER 2048
#define DSTATE 16
#define DCONV 4
#define MM (BB * LL)          // 2048
#define N_XZ 4096
#define N_SSM 2080
#define N_SSM_PAD 2176        // 34 * 64
#define CCH 32                // chunks over L
#define LCH 32                // chunk length (CCH*LCH == LL)

typedef __hip_bfloat16 bf16;
typedef short bf16x8 __attribute__((ext_vector_type(8)));
typedef float f32x4 __attribute__((ext_vector_type(4)));

// ---------------- async global -> LDS, 16B per lane ----------------
__device__ __forceinline__ void load16_lds(const bf16* g, bf16* l) {
    __builtin_amdgcn_global_load_lds(
        (const __attribute__((address_space(1))) void*)g,
        (__attribute__((address_space(3))) void*)l,
        16, 0, 0);
}

// ---------------- fp32 -> bf16 straight cast ----------------
__global__ void cvt_kernel(const float* __restrict__ in, bf16* __restrict__ out, int n) {
    int i = blockIdx.x * blockDim.x + threadIdx.x;
    if (i < n) out[i] = __float2bfloat16(in[i]);
}

// ---------------- transpose + cast: W fp32 [K,N] -> Wt bf16 [N,K] ----------------
__global__ void transpose_cvt_kernel(const float* __restrict__ in, bf16* __restrict__ out,
                                     int K, int N) {
    __shared__ float tile[32][33];
    const int nb = blockIdx.x * 32, kb = blockIdx.y * 32;
    const int tx = threadIdx.x & 31;
    const int ty = threadIdx.x >> 5;
    #pragma unroll
    for (int i = 0; i < 32; i += 8) {
        int k = kb + ty + i, n = nb + tx;
        tile[ty + i][tx] = (k < K && n < N) ? in[(size_t)k * N + n] : 0.f;
    }
    __syncthreads();
    #pragma unroll
    for (int i = 0; i < 32; i += 8) {
        int n = nb + ty + i, k = kb + tx;
        if (n < N && k < K) out[(size_t)n * K + k] = __float2bfloat16(tile[tx][ty + i]);
    }
}

// ---------------- MFMA GEMM v4: 128x64 tile, glds single-buffer, swizzled LDS -------
// C[M,N] = A[M,K](bf16) @ Wt[N,K](bf16)^T
// EPI: 0 = bf16 store (col<N guard), 1 = +bias softplus f32, 2 = f32 (atomic if KSPLIT>1),
//      3 = cols<32 -> f32 BC sideband, cols in [32,N) -> bf16
#define TM 128
#define TN 64
#define TK 32
template<int EPI, int KSPLIT = 1>
__global__ __launch_bounds__(256) void mfma_gemm(
    const bf16* __restrict__ A, int lda,
    const bf16* __restrict__ Wt, int ldw,
    float* __restrict__ Cf, bf16* __restrict__ Cb, int ldc,
    const float* __restrict__ bias,
    int N, int K)
{
    __shared__ __align__(16) bf16 As[TM * TK];   // 8 KB
    __shared__ __align__(16) bf16 Bs[TN * TK];   // 4 KB
    const int tid = threadIdx.x;
    const int wave = tid >> 6, lane = tid & 63;
    const int wm = (wave >> 1) * 64, wn = (wave & 1) * 32;
    const int m0 = blockIdx.y * TM, n0 = blockIdx.x * TN;
    const int lm = lane & 15, kq = lane >> 4;

    // staging: lane covers row srow of wave's 16-row slab, fetches swizzled chunk cg
    // (r9-verified: zero bank conflicts, correct results)
    const int srow = lane >> 2;
    const int cg = ((lane & 3) - ((srow >> 1) & 3)) & 3;
    const bf16* gA0 = A + (size_t)(m0 + wave * 16 + srow) * lda + cg * 8;        // rows 0-63
    const bf16* gA1 = A + (size_t)(m0 + wave * 16 + 64 + srow) * lda + cg * 8;   // rows 64-127
    const bf16* gB  = Wt + (size_t)(n0 + wave * 16 + srow) * ldw + cg * 8;
    bf16* As0 = &As[(wave * 16) * TK];
    bf16* As1 = &As[(wave * 16 + 64) * TK];
    bf16* Bs0 = &Bs[(wave * 16) * TK];

    // fragment-read slot (swizzle inverse): slot = (kq + (row>>1)) & 3
    const int soff = ((kq + ((lm >> 1) & 3)) & 3) * 8;

    const int Kc = K / KSPLIT;
    const int kbeg = (KSPLIT > 1) ? blockIdx.z * Kc : 0;

    f32x4 acc[4][2] = {};

    for (int it = 0; it < Kc; it += TK) {
        const int k0 = kbeg + it;
        load16_lds(gA0 + k0, As0);
        load16_lds(gA1 + k0, As1);
        load16_lds(gB + k0, Bs0);
        __syncthreads();   // drains vmcnt (glds) + lgkm

        bf16x8 af[4], bfr[2];
        #pragma unroll
        for (int i = 0; i < 4; ++i)
            af[i] = *(const bf16x8*)(&As[(wm + i * 16 + lm) * TK + soff]);
        #pragma unroll
        for (int j = 0; j < 2; ++j)
            bfr[j] = *(const bf16x8*)(&Bs[(wn + j * 16 + lm) * TK + soff]);
        #pragma unroll
        for (int i = 0; i < 4; ++i)
            #pragma unroll
            for (int j = 0; j < 2; ++j)
                acc[i][j] = __builtin_amdgcn_mfma_f32_16x16x32_bf16(af[i], bfr[j], acc[i][j], 0, 0, 0);
        __syncthreads();
    }

    // D layout: col = lane&15, row = (lane>>4)*4 + r (m89-verified)
    #pragma unroll
    for (int i = 0; i < 4; ++i) {
        #pragma unroll
        for (int j = 0; j < 2; ++j) {
            int gcol = n0 + wn + j * 16 + lm;
            if ((EPI == 0 || EPI == 3) && gcol >= N) continue;
            #pragma unroll
            for (int r = 0; r < 4; ++r) {
                int grow = m0 + wm + i * 16 + kq * 4 + r;
                float v = acc[i][j][r];
                if (EPI == 1) {
                    v += bias[gcol];
                    v = (v > 20.f) ? v : log1pf(__expf(v));
                    Cf[(size_t)grow * ldc + gcol] = v;
                } else if (EPI == 2) {
                    if (KSPLIT > 1) atomicAdd(&Cf[(size_t)grow * ldc + gcol], v);
                    else            Cf[(size_t)grow * ldc + gcol] = v;
                } else if (EPI == 3) {
                    if (gcol < 32) Cf[(size_t)grow * 32 + gcol] = v;     // BC f32 sideband
                    else           Cb[(size_t)grow * ldc + gcol] = __float2bfloat16(v);
                } else {
                    Cb[(size_t)grow * ldc + gcol] = __float2bfloat16(v);
                }
            }
        }
    }
}

// ---------------- depthwise causal conv (k=4) + bias + SiLU (bf16 io) ----------------
__global__ void conv_silu_kernel(const bf16* __restrict__ xz,
                                 const float* __restrict__ conv_w,
                                 const float* __restrict__ conv_b,
                                 bf16* __restrict__ u)
{
    int idx = blockIdx.x * blockDim.x + threadIdx.x;
    if (idx >= BB * LL * DINNER) return;
    int d = idx & (DINNER - 1);
    int l = (idx >> 11) & (LL - 1);
    int b = idx >> 21;
    float acc = conv_b[d];
    #pragma unroll
    for (int j = 0; j < DCONV; ++j) {
        int ll = l - (DCONV - 1) + j;
        if (ll >= 0) {
            float xv = (float)xz[((size_t)(b * LL + ll)) * N_XZ + d];
            acc = fmaf(conv_w[d * DCONV + j], xv, acc);
        }
    }
    u[idx] = __float2bfloat16(acc / (1.f + __expf(-acc)));
}

// ---------------- scan phase A: lane per (b,d,chunk), h[16] in regs ----------------
__global__ __launch_bounds__(256) void scan_phase_a(
    const float* __restrict__ dt, const bf16* __restrict__ u,
    const float* __restrict__ BC,    // (B,L,32) f32: B=[0:16), C=[16:32)
    const float* __restrict__ A_log,
    float* __restrict__ chunkP, float* __restrict__ chunkH)
{
    const int d = blockIdx.x * 256 + threadIdx.x;
    const int c = blockIdx.y, b = blockIdx.z;
    const int l0 = c * LCH;

    float A[DSTATE];
    {
        const f32x4* ap = (const f32x4*)(A_log + d * DSTATE);
        #pragma unroll
        for (int q = 0; q < 4; ++q) {
            f32x4 v = ap[q];
            #pragma unroll
            for (int r = 0; r < 4; ++r) A[q * 4 + r] = -__expf(v[r]);
        }
    }
    float h[DSTATE];
    #pragma unroll
    for (int n = 0; n < DSTATE; ++n) h[n] = 0.f;
    float sdt = 0.f;

    const float* dtp = dt + ((size_t)b * LL + l0) * DINNER + d;
    const bf16* up = u + ((size_t)b * LL + l0) * DINNER + d;
    const float* bcp = BC + ((size_t)b * LL + l0) * 32;

    #pragma unroll 2
    for (int i = 0; i < LCH; ++i) {
        float dtv = *dtp;
        float uv  = (float)*up;
        float du  = dtv * uv;
        f32x4 Bv[4];
        #pragma unroll
        for (int q = 0; q < 4; ++q) Bv[q] = *(const f32x4*)(bcp + q * 4);
        #pragma unroll
        for (int n = 0; n < DSTATE; ++n) {
            float a = __expf(dtv * A[n]);
            h[n] = fmaf(a, h[n], du * Bv[n >> 2][n & 3]);
        }
        sdt += dtv;
        dtp += DINNER; up += DINNER; bcp += 32;
    }

    size_t idx = (((size_t)b * CCH + c) * DINNER + d) * DSTATE;
    #pragma unroll
    for (int q = 0; q < 4; ++q) {
        f32x4 pv, hv;
        #pragma unroll
        for (int r = 0; r < 4; ++r) { pv[r] = __expf(A[q * 4 + r] * sdt); hv[r] = h[q * 4 + r]; }
        *(f32x4*)(chunkP + idx + q * 4) = pv;
        *(f32x4*)(chunkH + idx + q * 4) = hv;
    }
}

// ---------------- scan phase P: exclusive prefix over chunks, in place on chunkH ----
__global__ __launch_bounds__(256) void scan_phase_p(
    const float* __restrict__ chunkP, float* __restrict__ chunkH)
{
    int gid = blockIdx.x * 256 + threadIdx.x;   // over B*DINNER*DSTATE = 65536
    int n = gid & 15;
    int d = (gid >> 4) & (DINNER - 1);
    int b = gid >> 15;
    const size_t stride = (size_t)DINNER * DSTATE;
    size_t idx = ((size_t)b * CCH * DINNER + d) * DSTATE + n;
    float H = 0.f;
    for (int c = 0; c < CCH; ++c) {
        float P  = chunkP[idx];
        float hl = chunkH[idx];
        chunkH[idx] = H;           // exclusive prefix
        H = fmaf(P, H, hl);
        idx += stride;
    }
}

// ---------------- scan phase B: lane per (b,d,chunk); gated y over u --------
__global__ __launch_bounds__(256) void scan_phase_b(
    const float* __restrict__ dt, bf16* __restrict__ u,
    const float* __restrict__ BC, const bf16* __restrict__ xz,
    const float* __restrict__ A_log, const float* __restrict__ Dp,
    const float* __restrict__ chunkH)
{
    const int d = blockIdx.x * 256 + threadIdx.x;
    const int c = blockIdx.y, b = blockIdx.z;
    const int l0 = c * LCH;

    float A[DSTATE];
    {
        const f32x4* ap = (const f32x4*)(A_log + d * DSTATE);
        #pragma unroll
        for (int q = 0; q < 4; ++q) {
            f32x4 v = ap[q];
            #pragma unroll
            for (int r = 0; r < 4; ++r) A[q * 4 + r] = -__expf(v[r]);
        }
    }
    const float Dd = Dp[d];
    float h[DSTATE];
    {
        size_t idx = (((size_t)b * CCH + c) * DINNER + d) * DSTATE;
        #pragma unroll
        for (int q = 0; q < 4; ++q) {
            f32x4 v = *(const f32x4*)(chunkH + idx + q * 4);
            #pragma unroll
            for (int r = 0; r < 4; ++r) h[q * 4 + r] = v[r];
        }
    }

    const float* dtp = dt + ((size_t)b * LL + l0) * DINNER + d;
    bf16* up = u + ((size_t)b * LL + l0) * DINNER + d;
    const float* bcp = BC + ((size_t)b * LL + l0) * 32;
    const bf16* zp = xz + ((size_t)b * LL + l0) * N_XZ + DINNER + d;

    #pragma unroll 2
    for (int i = 0; i < LCH; ++i) {
        float dtv = *dtp;
        float uv  = (float)*up;
        float du  = dtv * uv;
        f32x4 Bv[4], Cv[4];
        #pragma unroll
        for (int q = 0; q < 4; ++q) {
            Bv[q] = *(const f32x4*)(bcp + q * 4);
            Cv[q] = *(const f32x4*)(bcp + 16 + q * 4);
        }
        float acc = 0.f;
        #pragma unroll
        for (int n = 0; n < DSTATE; ++n) {
            float a = __expf(dtv * A[n]);
            h[n] = fmaf(a, h[n], du * Bv[n >> 2][n & 3]);
            acc = fmaf(h[n], Cv[n >> 2][n & 3], acc);
        }
        float zv = (float)*zp;
        acc = fmaf(Dd, uv, acc);
        acc *= zv / (1.f + __expf(-zv));
        *up = __float2bfloat16(acc);
        dtp += DINNER; up += DINNER; bcp += 32; zp += N_XZ;
    }
}

extern "C" void kernel_launch(void* const* d_in, const int* in_sizes, int n_in,
                              void* d_out, int out_size, void* d_ws, size_t ws_size,
                              hipStream_t stream) {
    const float* x         = (const float*)d_in[0];
    const float* in_proj_w = (const float*)d_in[1];
    const float* conv_w    = (const float*)d_in[2];
    const float* conv_b    = (const float*)d_in[3];
    const float* x_proj_w  = (const float*)d_in[4];
    const float* dt_proj_w = (const float*)d_in[5];
    const float* dt_proj_b = (const float*)d_in[6];
    const float* A_log     = (const float*)d_in[7];
    const float* Dp        = (const float*)d_in[8];
    const float* out_proj_w= (const float*)d_in[9];
    float* out = (float*)d_out;

    // workspace layout (~80.7 MB); xbf aliases dt; chunkP/H alias Wt1/Wt2
    char* p = (char*)d_ws;
    float* dt   = (float*)p;                          p += (size_t)MM * DINNER * 4;
    bf16*  xbf  = (bf16*)dt;
    bf16*  xz   = (bf16*)p;                           p += (size_t)MM * N_XZ * 2;
    bf16*  u    = (bf16*)p;                           p += (size_t)MM * DINNER * 2;
    bf16*  ssm  = (bf16*)p;                           p += (size_t)MM * N_SSM * 2;
    bf16*  Wt1  = (bf16*)p;                           p += (size_t)N_XZ * DMODEL * 2;      // 8 MB
    bf16*  Wt2  = (bf16*)p;                           p += (size_t)N_SSM_PAD * DINNER * 2; // 8.9 MB
    bf16*  Wt3  = (bf16*)p;                           p += (size_t)DINNER * DINNER * 2;
    bf16*  Wt4  = (bf16*)p;                           p += (size_t)DMODEL * DINNER * 2;
    float* BC   = (float*)p;                          p += (size_t)MM * 32 * 4;            // 256 KB
    float* chunkP = (float*)Wt1;   // B*CCH*DINNER*16 f32 = 8 MB exactly
    float* chunkH = (float*)Wt2;   // 8 MB of Wt2's 8.9

    // 0) converts / transposes
    {
        int n = MM * DMODEL;
        cvt_kernel<<<(n + 255) / 256, 256, 0, stream>>>(x, xbf, n);
        transpose_cvt_kernel<<<dim3(N_XZ / 32, DMODEL / 32), 256, 0, stream>>>(in_proj_w, Wt1, DMODEL, N_XZ);
        transpose_cvt_kernel<<<dim3((N_SSM + 31) / 32, DINNER / 32), 256, 0, stream>>>(x_proj_w, Wt2, DINNER, N_SSM);
        transpose_cvt_kernel<<<dim3(DINNER / 32, DINNER / 32), 256, 0, stream>>>(dt_proj_w, Wt3, DINNER, DINNER);
        transpose_cvt_kernel<<<dim3(DMODEL / 32, DINNER / 32), 256, 0, stream>>>(out_proj_w, Wt4, DINNER, DMODEL);
    }
    // 1) xz = xbf @ W1   (2048 x 4096, K=1024), bf16  — grid 64x16 = 1024 blocks
    mfma_gemm<0><<<dim3(N_XZ / TN, MM / TM), 256, 0, stream>>>(
        xbf, DMODEL, Wt1, DMODEL, nullptr, xz, N_XZ, nullptr, N_XZ, DMODEL);
    // 2) u = silu(conv(x_inner)+b)
    {
        int n = BB * LL * DINNER;
        conv_silu_kernel<<<(n + 255) / 256, 256, 0, stream>>>(xz, conv_w, conv_b, u);
    }
    // 3) ssm = u @ W2    (2048 x 2080, K=2048); cols<32 -> BC f32, rest bf16 — 544 blocks
    mfma_gemm<3><<<dim3(N_SSM_PAD / TN, MM / TM), 256, 0, stream>>>(
        u, DINNER, Wt2, DINNER, BC, ssm, N_SSM, nullptr, N_SSM, DINNER);
    // 4) dt = softplus(ssm[:,32:] @ W3 + b)  (2048 x 2048, K=2048), fp32 — 512 blocks
    mfma_gemm<1><<<dim3(DINNER / TN, MM / TM), 256, 0, stream>>>(
        ssm + 2 * DSTATE, N_SSM, Wt3, DINNER, dt, nullptr, DINNER, dt_proj_b, DINNER, DINNER);
    // 5) chunked selective scan: A (local), P (prefix), B (apply; y over u)
    scan_phase_a<<<dim3(DINNER / 256, CCH, BB), 256, 0, stream>>>(dt, u, BC, A_log, chunkP, chunkH);
    scan_phase_p<<<dim3(BB * DINNER * DSTATE / 256), 256, 0, stream>>>(chunkP, chunkH);
    scan_phase_b<<<dim3(DINNER / 256, CCH, BB), 256, 0, stream>>>(dt, u, BC, xz, A_log, Dp, chunkH);
    // 6) out = y @ W4    (2048 x 1024, K=2048), fp32, split-K=2 atomic — 512 blocks
    hipMemsetAsync(out, 0, (size_t)out_size * sizeof(float), stream);
    mfma_gemm<2, 2><<<dim3(DMODEL / TN, MM / TM, 2), 256, 0, stream>>>(
        u, DINNER, Wt4, DINNER, out, nullptr, DMODEL, nullptr, DMODEL, DINNER);
}

// Round 11
// 339.996 us; speedup vs baseline: 1.1510x; 1.1021x over previous
//
#include <hip/hip_runtime.h>
#include <hip/hip_bf16.h>

// Dims (fixed for this problem)
#define BB 2
#define LL 1024
#define DMODEL 1024
#define DINNER 2048
#define DSTATE 16
#define DCONV 4
#define MM (BB * LL)          // 2048
#define N_XZ 4096
#define N_SSM 2080
#define N_SSM_PAD 2176        // 34 * 64
#define CCH 32                // chunks over L
#define LCH 32                // chunk length (CCH*LCH == LL)

typedef __hip_bfloat16 bf16;
typedef short bf16x8 __attribute__((ext_vector_type(8)));
typedef float f32x4 __attribute__((ext_vector_type(4)));

// ---------------- async global -> LDS, 16B per lane ----------------
__device__ __forceinline__ void load16_lds(const bf16* g, bf16* l) {
    __builtin_amdgcn_global_load_lds(
        (const __attribute__((address_space(1))) void*)g,
        (__attribute__((address_space(3))) void*)l,
        16, 0, 0);
}

// ---------------- fused prep: 4 weight transposes (f32[K,N] -> bf16[N,K]) + x cvt ----
// grid.x = 4096 (W1) + 4160 (W2) + 4096 (W3) + 2048 (W4) + 2048 (cvt) = 16448
__global__ __launch_bounds__(256) void prep_kernel(
    const float* __restrict__ x, bf16* __restrict__ xbf,
    const float* __restrict__ w1, bf16* __restrict__ o1,
    const float* __restrict__ w2, bf16* __restrict__ o2,
    const float* __restrict__ w3, bf16* __restrict__ o3,
    const float* __restrict__ w4, bf16* __restrict__ o4)
{
    int bid = blockIdx.x;
    const float* src; bf16* dst; int K, N, tn, tk;
    if (bid < 4096)        { src = w1; dst = o1; K = 1024; N = 4096; tn = bid & 127; tk = bid >> 7; }
    else if (bid < 8256)   { bid -= 4096;  src = w2; dst = o2; K = 2048; N = 2080; tn = bid % 65; tk = bid / 65; }
    else if (bid < 12352)  { bid -= 8256;  src = w3; dst = o3; K = 2048; N = 2048; tn = bid & 63; tk = bid >> 6; }
    else if (bid < 14400)  { bid -= 12352; src = w4; dst = o4; K = 2048; N = 1024; tn = bid & 31; tk = bid >> 5; }
    else {
        bid -= 14400;   // cvt: 2048 blocks x 1024 elems
        int i = (bid * 256 + threadIdx.x) * 4;
        float4 v = *(const float4*)(x + i);
        xbf[i + 0] = __float2bfloat16(v.x);
        xbf[i + 1] = __float2bfloat16(v.y);
        xbf[i + 2] = __float2bfloat16(v.z);
        xbf[i + 3] = __float2bfloat16(v.w);
        return;
    }
    __shared__ float tile[32][33];
    const int nb = tn * 32, kb = tk * 32;
    const int tx = threadIdx.x & 31, ty = threadIdx.x >> 5;
    #pragma unroll
    for (int i = 0; i < 32; i += 8) {
        int k = kb + ty + i, n = nb + tx;
        tile[ty + i][tx] = (k < K && n < N) ? src[(size_t)k * N + n] : 0.f;
    }
    __syncthreads();
    #pragma unroll
    for (int i = 0; i < 32; i += 8) {
        int n = nb + ty + i, k = kb + tx;
        if (n < N && k < K) dst[(size_t)n * K + k] = __float2bfloat16(tile[tx][ty + i]);
    }
}

// ---------------- MFMA GEMM v5: 128x64 tile, TK=64 (half the barrier drains) -------
// C[M,N] = A[M,K](bf16) @ Wt[N,K](bf16)^T ; glds staging, XOR-swizzled LDS rows
// EPI: 0 = bf16 store (col<N guard), 1 = +bias softplus f32, 2 = f32 (atomic if KSPLIT>1),
//      3 = cols<32 -> f32 BC sideband, cols in [32,N) -> bf16
#define TM 128
#define TN 64
#define TK 64
template<int EPI, int KSPLIT = 1>
__global__ __launch_bounds__(256) void mfma_gemm(
    const bf16* __restrict__ A, int lda,
    const bf16* __restrict__ Wt, int ldw,
    float* __restrict__ Cf, bf16* __restrict__ Cb, int ldc,
    const float* __restrict__ bias,
    int N, int K)
{
    __shared__ __align__(16) bf16 As[TM * TK];   // 16 KB
    __shared__ __align__(16) bf16 Bs[TN * TK];   // 8 KB
    const int tid = threadIdx.x;
    const int wave = tid >> 6, lane = tid & 63;
    const int wm = (wave >> 1) * 64, wn = (wave & 1) * 32;
    const int m0 = blockIdx.y * TM, n0 = blockIdx.x * TN;
    const int lm = lane & 15, kq = lane >> 4;

    // staging: per glds, lane covers row (lane>>3), swizzled chunk (lane&7)^(lane>>3)
    // row stride 128 B; XOR keeps frag reads 2-way (free) on 32 banks
    const int srow = lane >> 3;
    const int schunk = (lane & 7) ^ srow;
    const bf16* gA = A + (size_t)(m0 + wave * 32 + srow) * lda + schunk * 8;
    const bf16* gB = Wt + (size_t)(n0 + wave * 16 + srow) * ldw + schunk * 8;
    bf16* lA = &As[(wave * 32) * TK];
    bf16* lB = &Bs[(wave * 16) * TK];

    const int Kc = K / KSPLIT;
    const int kbeg = (KSPLIT > 1) ? blockIdx.z * Kc : 0;

    f32x4 acc[4][2] = {};
    const int fsw = (lm & 7);   // frag-read XOR key

    for (int it = 0; it < Kc; it += TK) {
        const int k0 = kbeg + it;
        #pragma unroll
        for (int g = 0; g < 4; ++g)
            load16_lds(gA + (size_t)(8 * g) * lda + k0, lA + (8 * g) * TK);
        #pragma unroll
        for (int g = 0; g < 2; ++g)
            load16_lds(gB + (size_t)(8 * g) * ldw + k0, lB + (8 * g) * TK);
        __syncthreads();   // drains vmcnt (glds) — 16 drains total vs 32 at TK=32

        bf16x8 af[4][2], bfr[2][2];
        #pragma unroll
        for (int i = 0; i < 4; ++i)
            #pragma unroll
            for (int t = 0; t < 2; ++t)
                af[i][t] = *(const bf16x8*)(&As[(wm + i * 16 + lm) * TK + ((t * 4 + kq) ^ fsw) * 8]);
        #pragma unroll
        for (int j = 0; j < 2; ++j)
            #pragma unroll
            for (int t = 0; t < 2; ++t)
                bfr[j][t] = *(const bf16x8*)(&Bs[(wn + j * 16 + lm) * TK + ((t * 4 + kq) ^ fsw) * 8]);
        #pragma unroll
        for (int t = 0; t < 2; ++t)
            #pragma unroll
            for (int i = 0; i < 4; ++i)
                #pragma unroll
                for (int j = 0; j < 2; ++j)
                    acc[i][j] = __builtin_amdgcn_mfma_f32_16x16x32_bf16(af[i][t], bfr[j][t], acc[i][j], 0, 0, 0);
        __syncthreads();
    }

    // D layout: col = lane&15, row = (lane>>4)*4 + r (m89-verified)
    #pragma unroll
    for (int i = 0; i < 4; ++i) {
        #pragma unroll
        for (int j = 0; j < 2; ++j) {
            int gcol = n0 + wn + j * 16 + lm;
            if ((EPI == 0 || EPI == 3) && gcol >= N) continue;
            #pragma unroll
            for (int r = 0; r < 4; ++r) {
                int grow = m0 + wm + i * 16 + kq * 4 + r;
                float v = acc[i][j][r];
                if (EPI == 1) {
                    v += bias[gcol];
                    v = (v > 20.f) ? v : log1pf(__expf(v));
                    Cf[(size_t)grow * ldc + gcol] = v;
                } else if (EPI == 2) {
                    if (KSPLIT > 1) atomicAdd(&Cf[(size_t)grow * ldc + gcol], v);
                    else            Cf[(size_t)grow * ldc + gcol] = v;
                } else if (EPI == 3) {
                    if (gcol < 32) Cf[(size_t)grow * 32 + gcol] = v;     // BC f32 sideband
                    else           Cb[(size_t)grow * ldc + gcol] = __float2bfloat16(v);
                } else {
                    Cb[(size_t)grow * ldc + gcol] = __float2bfloat16(v);
                }
            }
        }
    }
}

// ---------------- depthwise causal conv (k=4) + bias + SiLU (bf16 io) ----------------
__global__ void conv_silu_kernel(const bf16* __restrict__ xz,
                                 const float* __restrict__ conv_w,
                                 const float* __restrict__ conv_b,
                                 bf16* __restrict__ u)
{
    int idx = blockIdx.x * blockDim.x + threadIdx.x;
    if (idx >= BB * LL * DINNER) return;
    int d = idx & (DINNER - 1);
    int l = (idx >> 11) & (LL - 1);
    int b = idx >> 21;
    float acc = conv_b[d];
    #pragma unroll
    for (int j = 0; j < DCONV; ++j) {
        int ll = l - (DCONV - 1) + j;
        if (ll >= 0) {
            float xv = (float)xz[((size_t)(b * LL + ll)) * N_XZ + d];
            acc = fmaf(conv_w[d * DCONV + j], xv, acc);
        }
    }
    u[idx] = __float2bfloat16(acc / (1.f + __expf(-acc)));
}

// ---------------- scan phase A: lane per (b,d,chunk), h[16] in regs ----------------
__global__ __launch_bounds__(256) void scan_phase_a(
    const float* __restrict__ dt, const bf16* __restrict__ u,
    const float* __restrict__ BC,    // (B,L,32) f32: B=[0:16), C=[16:32)
    const float* __restrict__ A_log,
    float* __restrict__ chunkP, float* __restrict__ chunkH)
{
    const int d = blockIdx.x * 256 + threadIdx.x;
    const int c = blockIdx.y, b = blockIdx.z;
    const int l0 = c * LCH;

    float A[DSTATE];
    {
        const f32x4* ap = (const f32x4*)(A_log + d * DSTATE);
        #pragma unroll
        for (int q = 0; q < 4; ++q) {
            f32x4 v = ap[q];
            #pragma unroll
            for (int r = 0; r < 4; ++r) A[q * 4 + r] = -__expf(v[r]);
        }
    }
    float h[DSTATE];
    #pragma unroll
    for (int n = 0; n < DSTATE; ++n) h[n] = 0.f;
    float sdt = 0.f;

    const float* dtp = dt + ((size_t)b * LL + l0) * DINNER + d;
    const bf16* up = u + ((size_t)b * LL + l0) * DINNER + d;
    const float* bcp = BC + ((size_t)b * LL + l0) * 32;

    #pragma unroll 2
    for (int i = 0; i < LCH; ++i) {
        float dtv = *dtp;
        float uv  = (float)*up;
        float du  = dtv * uv;
        f32x4 Bv[4];
        #pragma unroll
        for (int q = 0; q < 4; ++q) Bv[q] = *(const f32x4*)(bcp + q * 4);
        #pragma unroll
        for (int n = 0; n < DSTATE; ++n) {
            float a = __expf(dtv * A[n]);
            h[n] = fmaf(a, h[n], du * Bv[n >> 2][n & 3]);
        }
        sdt += dtv;
        dtp += DINNER; up += DINNER; bcp += 32;
    }

    size_t idx = (((size_t)b * CCH + c) * DINNER + d) * DSTATE;
    #pragma unroll
    for (int q = 0; q < 4; ++q) {
        f32x4 pv, hv;
        #pragma unroll
        for (int r = 0; r < 4; ++r) { pv[r] = __expf(A[q * 4 + r] * sdt); hv[r] = h[q * 4 + r]; }
        *(f32x4*)(chunkP + idx + q * 4) = pv;
        *(f32x4*)(chunkH + idx + q * 4) = hv;
    }
}

// ---------------- scan phase P: exclusive prefix over chunks, in place on chunkH ----
__global__ __launch_bounds__(256) void scan_phase_p(
    const float* __restrict__ chunkP, float* __restrict__ chunkH)
{
    int gid = blockIdx.x * 256 + threadIdx.x;   // over B*DINNER*DSTATE = 65536
    int n = gid & 15;
    int d = (gid >> 4) & (DINNER - 1);
    int b = gid >> 15;
    const size_t stride = (size_t)DINNER * DSTATE;
    size_t idx = ((size_t)b * CCH * DINNER + d) * DSTATE + n;
    float H = 0.f;
    for (int c = 0; c < CCH; ++c) {
        float P  = chunkP[idx];
        float hl = chunkH[idx];
        chunkH[idx] = H;           // exclusive prefix
        H = fmaf(P, H, hl);
        idx += stride;
    }
}

// ---------------- scan phase B: lane per (b,d,chunk); gated y over u --------
__global__ __launch_bounds__(256) void scan_phase_b(
    const float* __restrict__ dt, bf16* __restrict__ u,
    const float* __restrict__ BC, const bf16* __restrict__ xz,
    const float* __restrict__ A_log, const float* __restrict__ Dp,
    const float* __restrict__ chunkH)
{
    const int d = blockIdx.x * 256 + threadIdx.x;
    const int c = blockIdx.y, b = blockIdx.z;
    const int l0 = c * LCH;

    float A[DSTATE];
    {
        const f32x4* ap = (const f32x4*)(A_log + d * DSTATE);
        #pragma unroll
        for (int q = 0; q < 4; ++q) {
            f32x4 v = ap[q];
            #pragma unroll
            for (int r = 0; r < 4; ++r) A[q * 4 + r] = -__expf(v[r]);
        }
    }
    const float Dd = Dp[d];
    float h[DSTATE];
    {
        size_t idx = (((size_t)b * CCH + c) * DINNER + d) * DSTATE;
        #pragma unroll
        for (int q = 0; q < 4; ++q) {
            f32x4 v = *(const f32x4*)(chunkH + idx + q * 4);
            #pragma unroll
            for (int r = 0; r < 4; ++r) h[q * 4 + r] = v[r];
        }
    }

    const float* dtp = dt + ((size_t)b * LL + l0) * DINNER + d;
    bf16* up = u + ((size_t)b * LL + l0) * DINNER + d;
    const float* bcp = BC + ((size_t)b * LL + l0) * 32;
    const bf16* zp = xz + ((size_t)b * LL + l0) * N_XZ + DINNER + d;

    #pragma unroll 2
    for (int i = 0; i < LCH; ++i) {
        float dtv = *dtp;
        float uv  = (float)*up;
        float du  = dtv * uv;
        f32x4 Bv[4], Cv[4];
        #pragma unroll
        for (int q = 0; q < 4; ++q) {
            Bv[q] = *(const f32x4*)(bcp + q * 4);
            Cv[q] = *(const f32x4*)(bcp + 16 + q * 4);
        }
        float acc = 0.f;
        #pragma unroll
        for (int n = 0; n < DSTATE; ++n) {
            float a = __expf(dtv * A[n]);
            h[n] = fmaf(a, h[n], du * Bv[n >> 2][n & 3]);
            acc = fmaf(h[n], Cv[n >> 2][n & 3], acc);
        }
        float zv = (float)*zp;
        acc = fmaf(Dd, uv, acc);
        acc *= zv / (1.f + __expf(-zv));
        *up = __float2bfloat16(acc);
        dtp += DINNER; up += DINNER; bcp += 32; zp += N_XZ;
    }
}

extern "C" void kernel_launch(void* const* d_in, const int* in_sizes, int n_in,
                              void* d_out, int out_size, void* d_ws, size_t ws_size,
                              hipStream_t stream) {
    const float* x         = (const float*)d_in[0];
    const float* in_proj_w = (const float*)d_in[1];
    const float* conv_w    = (const float*)d_in[2];
    const float* conv_b    = (const float*)d_in[3];
    const float* x_proj_w  = (const float*)d_in[4];
    const float* dt_proj_w = (const float*)d_in[5];
    const float* dt_proj_b = (const float*)d_in[6];
    const float* A_log     = (const float*)d_in[7];
    const float* Dp        = (const float*)d_in[8];
    const float* out_proj_w= (const float*)d_in[9];
    float* out = (float*)d_out;

    // workspace layout (~80.7 MB); xbf aliases dt; chunkP/H alias Wt1/Wt2
    char* p = (char*)d_ws;
    float* dt   = (float*)p;                          p += (size_t)MM * DINNER * 4;
    bf16*  xbf  = (bf16*)dt;
    bf16*  xz   = (bf16*)p;                           p += (size_t)MM * N_XZ * 2;
    bf16*  u    = (bf16*)p;                           p += (size_t)MM * DINNER * 2;
    bf16*  ssm  = (bf16*)p;                           p += (size_t)MM * N_SSM * 2;
    bf16*  Wt1  = (bf16*)p;                           p += (size_t)N_XZ * DMODEL * 2;      // 8 MB
    bf16*  Wt2  = (bf16*)p;                           p += (size_t)N_SSM_PAD * DINNER * 2; // 8.9 MB
    bf16*  Wt3  = (bf16*)p;                           p += (size_t)DINNER * DINNER * 2;
    bf16*  Wt4  = (bf16*)p;                           p += (size_t)DMODEL * DINNER * 2;
    float* BC   = (float*)p;                          p += (size_t)MM * 32 * 4;            // 256 KB
    float* chunkP = (float*)Wt1;   // B*CCH*DINNER*16 f32 = 8 MB exactly
    float* chunkH = (float*)Wt2;   // 8 MB of Wt2's 8.9

    // 0) fused prep: 4 transposes + x cvt in one launch
    prep_kernel<<<16448, 256, 0, stream>>>(x, xbf, in_proj_w, Wt1, x_proj_w, Wt2,
                                           dt_proj_w, Wt3, out_proj_w, Wt4);
    // 1) xz = xbf @ W1   (2048 x 4096, K=1024), bf16  — grid 64x16 = 1024 blocks
    mfma_gemm<0><<<dim3(N_XZ / TN, MM / TM), 256, 0, stream>>>(
        xbf, DMODEL, Wt1, DMODEL, nullptr, xz, N_XZ, nullptr, N_XZ, DMODEL);
    // 2) u = silu(conv(x_inner)+b)
    {
        int n = BB * LL * DINNER;
        conv_silu_kernel<<<(n + 255) / 256, 256, 0, stream>>>(xz, conv_w, conv_b, u);
    }
    // 3) ssm = u @ W2    (2048 x 2080, K=2048); cols<32 -> BC f32, rest bf16 — 544 blocks
    mfma_gemm<3><<<dim3(N_SSM_PAD / TN, MM / TM), 256, 0, stream>>>(
        u, DINNER, Wt2, DINNER, BC, ssm, N_SSM, nullptr, N_SSM, DINNER);
    // 4) dt = softplus(ssm[:,32:] @ W3 + b)  (2048 x 2048, K=2048), fp32 — 512 blocks
    mfma_gemm<1><<<dim3(DINNER / TN, MM / TM), 256, 0, stream>>>(
        ssm + 2 * DSTATE, N_SSM, Wt3, DINNER, dt, nullptr, DINNER, dt_proj_b, DINNER, DINNER);
    // 5) chunked selective scan: A (local), P (prefix), B (apply; y over u)
    scan_phase_a<<<dim3(DINNER / 256, CCH, BB), 256, 0, stream>>>(dt, u, BC, A_log, chunkP, chunkH);
    scan_phase_p<<<dim3(BB * DINNER * DSTATE / 256), 256, 0, stream>>>(chunkP, chunkH);
    scan_phase_b<<<dim3(DINNER / 256, CCH, BB), 256, 0, stream>>>(dt, u, BC, xz, A_log, Dp, chunkH);
    // 6) out = y @ W4    (2048 x 1024, K=2048), fp32, split-K=2 atomic — 512 blocks
    hipMemsetAsync(out, 0, (size_t)out_size * sizeof(float), stream);
    mfma_gemm<2, 2><<<dim3(DMODEL / TN, MM / TM, 2), 256, 0, stream>>>(
        u, DINNER, Wt4, DINNER, out, nullptr, DMODEL, nullptr, DMODEL, DINNER);
}

// Round 12
// 333.141 us; speedup vs baseline: 1.1747x; 1.0206x over previous
//
#include <hip/hip_runtime.h>
#include <hip/hip_bf16.h>

// Dims (fixed for this problem)
#define BB 2
#define LL 1024
#define DMODEL 1024
#define DINNER 2048
#define DSTATE 16
#define DCONV 4
#define MM (BB * LL)          // 2048
#define N_XZ 4096
#define N_SSM 2080
#define N_SSM_PAD 2176        // 34 * 64
#define CCH 32                // chunks over L
#define LCH 32                // chunk length (CCH*LCH == LL)

typedef __hip_bfloat16 bf16;
typedef short bf16x8 __attribute__((ext_vector_type(8)));
typedef float f32x4 __attribute__((ext_vector_type(4)));

// ---------------- async global -> LDS, 16B per lane ----------------
__device__ __forceinline__ void load16_lds(const bf16* g, bf16* l) {
    __builtin_amdgcn_global_load_lds(
        (const __attribute__((address_space(1))) void*)g,
        (__attribute__((address_space(3))) void*)l,
        16, 0, 0);
}

// ---------------- fused prep: 4 weight transposes (f32[K,N] -> bf16[N,K]) + x cvt ----
__global__ __launch_bounds__(256) void prep_kernel(
    const float* __restrict__ x, bf16* __restrict__ xbf,
    const float* __restrict__ w1, bf16* __restrict__ o1,
    const float* __restrict__ w2, bf16* __restrict__ o2,
    const float* __restrict__ w3, bf16* __restrict__ o3,
    const float* __restrict__ w4, bf16* __restrict__ o4)
{
    int bid = blockIdx.x;
    const float* src; bf16* dst; int K, N, tn, tk;
    if (bid < 4096)        { src = w1; dst = o1; K = 1024; N = 4096; tn = bid & 127; tk = bid >> 7; }
    else if (bid < 8256)   { bid -= 4096;  src = w2; dst = o2; K = 2048; N = 2080; tn = bid % 65; tk = bid / 65; }
    else if (bid < 12352)  { bid -= 8256;  src = w3; dst = o3; K = 2048; N = 2048; tn = bid & 63; tk = bid >> 6; }
    else if (bid < 14400)  { bid -= 12352; src = w4; dst = o4; K = 2048; N = 1024; tn = bid & 31; tk = bid >> 5; }
    else {
        bid -= 14400;   // cvt: 2048 blocks x 1024 elems
        int i = (bid * 256 + threadIdx.x) * 4;
        float4 v = *(const float4*)(x + i);
        xbf[i + 0] = __float2bfloat16(v.x);
        xbf[i + 1] = __float2bfloat16(v.y);
        xbf[i + 2] = __float2bfloat16(v.z);
        xbf[i + 3] = __float2bfloat16(v.w);
        return;
    }
    __shared__ float tile[32][33];
    const int nb = tn * 32, kb = tk * 32;
    const int tx = threadIdx.x & 31, ty = threadIdx.x >> 5;
    #pragma unroll
    for (int i = 0; i < 32; i += 8) {
        int k = kb + ty + i, n = nb + tx;
        tile[ty + i][tx] = (k < K && n < N) ? src[(size_t)k * N + n] : 0.f;
    }
    __syncthreads();
    #pragma unroll
    for (int i = 0; i < 32; i += 8) {
        int n = nb + ty + i, k = kb + tx;
        if (n < N && k < K) dst[(size_t)n * K + k] = __float2bfloat16(tile[tx][ty + i]);
    }
}

// ---------------- MFMA GEMM v6: 128x64, TK=64, glds DOUBLE-buffer, XCD swizzle -----
// C[M,N] = A[M,K](bf16) @ Wt[N,K](bf16)^T
// EPI: 0 = bf16 store (col<N guard), 1 = +bias softplus f32, 2 = f32 (atomic if KSPLIT>1),
//      3 = cols<32 -> f32 BC sideband, cols in [32,N) -> bf16
// SWZ >= 0: XCD-aware remap, SWZ = log2(NX/8) (requires NX % 8 == 0, NX/8 pow2)
#define TM 128
#define TN 64
#define TK 64
template<int EPI, int KSPLIT = 1, int SWZ = -1>
__global__ __launch_bounds__(256) void mfma_gemm(
    const bf16* __restrict__ A, int lda,
    const bf16* __restrict__ Wt, int ldw,
    float* __restrict__ Cf, bf16* __restrict__ Cb, int ldc,
    const float* __restrict__ bias,
    int N, int K)
{
    __shared__ __align__(16) bf16 As[2][TM * TK];   // 2 x 16 KB
    __shared__ __align__(16) bf16 Bs[2][TN * TK];   // 2 x 8 KB  (48 KB total)
    const int tid = threadIdx.x;
    const int wave = tid >> 6, lane = tid & 63;
    const int wm = (wave >> 1) * 64, wn = (wave & 1) * 32;

    int bx, by;
    if (SWZ >= 0) {
        // bind XCD (id&7) to a contiguous N-range: weights per XCD fit L2
        int id = blockIdx.x + (int)(gridDim.x * blockIdx.y);
        int xcd = id & 7, slot = id >> 3;
        bx = (xcd << SWZ) + (slot & ((1 << SWZ) - 1));
        by = slot >> SWZ;
    } else { bx = blockIdx.x; by = blockIdx.y; }
    const int m0 = by * TM, n0 = bx * TN;
    const int lm = lane & 15, kq = lane >> 4;

    // staging: lane covers row (lane>>3), swizzled chunk (lane&7)^row
    const int srow = lane >> 3;
    const int schunk = (lane & 7) ^ srow;
    const bf16* gA = A + (size_t)(m0 + wave * 32 + srow) * lda + schunk * 8;
    const bf16* gB = Wt + (size_t)(n0 + wave * 16 + srow) * ldw + schunk * 8;

    const int Kc = K / KSPLIT;
    const int kbeg = (KSPLIT > 1) ? blockIdx.z * Kc : 0;
    const int NK = Kc / TK;   // 16 or 32 (even)

    f32x4 acc[4][2] = {};
    const int fsw = (lm & 7);   // frag-read XOR key

    auto stage = [&](int buf, int it) {
        const int k0 = kbeg + it * TK;
        bf16* lA = &As[buf][(wave * 32) * TK];
        bf16* lB = &Bs[buf][(wave * 16) * TK];
        #pragma unroll
        for (int g = 0; g < 4; ++g)
            load16_lds(gA + (size_t)(8 * g) * lda + k0, lA + (8 * g) * TK);
        #pragma unroll
        for (int g = 0; g < 2; ++g)
            load16_lds(gB + (size_t)(8 * g) * ldw + k0, lB + (8 * g) * TK);
    };
    auto compute = [&](int buf) {
        bf16x8 af[4][2], bfr[2][2];
        #pragma unroll
        for (int i = 0; i < 4; ++i)
            #pragma unroll
            for (int t = 0; t < 2; ++t)
                af[i][t] = *(const bf16x8*)(&As[buf][(wm + i * 16 + lm) * TK + ((t * 4 + kq) ^ fsw) * 8]);
        #pragma unroll
        for (int j = 0; j < 2; ++j)
            #pragma unroll
            for (int t = 0; t < 2; ++t)
                bfr[j][t] = *(const bf16x8*)(&Bs[buf][(wn + j * 16 + lm) * TK + ((t * 4 + kq) ^ fsw) * 8]);
        #pragma unroll
        for (int t = 0; t < 2; ++t)
            #pragma unroll
            for (int i = 0; i < 4; ++i)
                #pragma unroll
                for (int j = 0; j < 2; ++j)
                    acc[i][j] = __builtin_amdgcn_mfma_f32_16x16x32_bf16(af[i][t], bfr[j][t], acc[i][j], 0, 0, 0);
    };

    stage(0, 0);                                  // 6 loads in flight
    for (int it = 0; it < NK; it += 2) {
        stage(1, it + 1);                         // 12 in flight
        __builtin_amdgcn_s_waitcnt(0x0F76);       // vmcnt(6): buf0 done, buf1 flying
        __builtin_amdgcn_s_barrier();
        compute(0);
        __builtin_amdgcn_s_barrier();             // everyone done reading buf0
        if (it + 2 < NK) {
            stage(0, it + 2);
            __builtin_amdgcn_s_waitcnt(0x0F76);   // buf1 done, buf0 flying
        } else {
            __builtin_amdgcn_s_waitcnt(0x0F70);   // vmcnt(0)
        }
        __builtin_amdgcn_s_barrier();
        compute(1);
        __builtin_amdgcn_s_barrier();
    }

    // D layout: col = lane&15, row = (lane>>4)*4 + r (m89-verified)
    #pragma unroll
    for (int i = 0; i < 4; ++i) {
        #pragma unroll
        for (int j = 0; j < 2; ++j) {
            int gcol = n0 + wn + j * 16 + lm;
            if ((EPI == 0 || EPI == 3) && gcol >= N) continue;
            #pragma unroll
            for (int r = 0; r < 4; ++r) {
                int grow = m0 + wm + i * 16 + kq * 4 + r;
                float v = acc[i][j][r];
                if (EPI == 1) {
                    v += bias[gcol];
                    v = (v > 20.f) ? v : log1pf(__expf(v));
                    Cf[(size_t)grow * ldc + gcol] = v;
                } else if (EPI == 2) {
                    if (KSPLIT > 1) atomicAdd(&Cf[(size_t)grow * ldc + gcol], v);
                    else            Cf[(size_t)grow * ldc + gcol] = v;
                } else if (EPI == 3) {
                    if (gcol < 32) Cf[(size_t)grow * 32 + gcol] = v;     // BC f32 sideband
                    else           Cb[(size_t)grow * ldc + gcol] = __float2bfloat16(v);
                } else {
                    Cb[(size_t)grow * ldc + gcol] = __float2bfloat16(v);
                }
            }
        }
    }
}

// ---------------- depthwise causal conv (k=4) + bias + SiLU (bf16 io) ----------------
__global__ void conv_silu_kernel(const bf16* __restrict__ xz,
                                 const float* __restrict__ conv_w,
                                 const float* __restrict__ conv_b,
                                 bf16* __restrict__ u)
{
    int idx = blockIdx.x * blockDim.x + threadIdx.x;
    if (idx >= BB * LL * DINNER) return;
    int d = idx & (DINNER - 1);
    int l = (idx >> 11) & (LL - 1);
    int b = idx >> 21;
    float acc = conv_b[d];
    #pragma unroll
    for (int j = 0; j < DCONV; ++j) {
        int ll = l - (DCONV - 1) + j;
        if (ll >= 0) {
            float xv = (float)xz[((size_t)(b * LL + ll)) * N_XZ + d];
            acc = fmaf(conv_w[d * DCONV + j], xv, acc);
        }
    }
    u[idx] = __float2bfloat16(acc / (1.f + __expf(-acc)));
}

// ---------------- scan phase A: lane per (b,d,chunk), h[16] in regs ----------------
__global__ __launch_bounds__(256) void scan_phase_a(
    const float* __restrict__ dt, const bf16* __restrict__ u,
    const float* __restrict__ BC,    // (B,L,32) f32: B=[0:16), C=[16:32)
    const float* __restrict__ A_log,
    float* __restrict__ chunkP, float* __restrict__ chunkH)
{
    const int d = blockIdx.x * 256 + threadIdx.x;
    const int c = blockIdx.y, b = blockIdx.z;
    const int l0 = c * LCH;

    float A[DSTATE];
    {
        const f32x4* ap = (const f32x4*)(A_log + d * DSTATE);
        #pragma unroll
        for (int q = 0; q < 4; ++q) {
            f32x4 v = ap[q];
            #pragma unroll
            for (int r = 0; r < 4; ++r) A[q * 4 + r] = -__expf(v[r]);
        }
    }
    float h[DSTATE];
    #pragma unroll
    for (int n = 0; n < DSTATE; ++n) h[n] = 0.f;
    float sdt = 0.f;

    const float* dtp = dt + ((size_t)b * LL + l0) * DINNER + d;
    const bf16* up = u + ((size_t)b * LL + l0) * DINNER + d;
    const float* bcp = BC + ((size_t)b * LL + l0) * 32;

    #pragma unroll 2
    for (int i = 0; i < LCH; ++i) {
        float dtv = *dtp;
        float uv  = (float)*up;
        float du  = dtv * uv;
        f32x4 Bv[4];
        #pragma unroll
        for (int q = 0; q < 4; ++q) Bv[q] = *(const f32x4*)(bcp + q * 4);
        #pragma unroll
        for (int n = 0; n < DSTATE; ++n) {
            float a = __expf(dtv * A[n]);
            h[n] = fmaf(a, h[n], du * Bv[n >> 2][n & 3]);
        }
        sdt += dtv;
        dtp += DINNER; up += DINNER; bcp += 32;
    }

    size_t idx = (((size_t)b * CCH + c) * DINNER + d) * DSTATE;
    #pragma unroll
    for (int q = 0; q < 4; ++q) {
        f32x4 pv, hv;
        #pragma unroll
        for (int r = 0; r < 4; ++r) { pv[r] = __expf(A[q * 4 + r] * sdt); hv[r] = h[q * 4 + r]; }
        *(f32x4*)(chunkP + idx + q * 4) = pv;
        *(f32x4*)(chunkH + idx + q * 4) = hv;
    }
}

// ---------------- scan phase P: exclusive prefix over chunks, in place on chunkH ----
__global__ __launch_bounds__(256) void scan_phase_p(
    const float* __restrict__ chunkP, float* __restrict__ chunkH)
{
    int gid = blockIdx.x * 256 + threadIdx.x;   // over B*DINNER*DSTATE = 65536
    int n = gid & 15;
    int d = (gid >> 4) & (DINNER - 1);
    int b = gid >> 15;
    const size_t stride = (size_t)DINNER * DSTATE;
    size_t idx = ((size_t)b * CCH * DINNER + d) * DSTATE + n;
    float H = 0.f;
    for (int c = 0; c < CCH; ++c) {
        float P  = chunkP[idx];
        float hl = chunkH[idx];
        chunkH[idx] = H;           // exclusive prefix
        H = fmaf(P, H, hl);
        idx += stride;
    }
}

// ---------------- scan phase B: lane per (b,d,chunk); gated y over u --------
__global__ __launch_bounds__(256) void scan_phase_b(
    const float* __restrict__ dt, bf16* __restrict__ u,
    const float* __restrict__ BC, const bf16* __restrict__ xz,
    const float* __restrict__ A_log, const float* __restrict__ Dp,
    const float* __restrict__ chunkH)
{
    const int d = blockIdx.x * 256 + threadIdx.x;
    const int c = blockIdx.y, b = blockIdx.z;
    const int l0 = c * LCH;

    float A[DSTATE];
    {
        const f32x4* ap = (const f32x4*)(A_log + d * DSTATE);
        #pragma unroll
        for (int q = 0; q < 4; ++q) {
            f32x4 v = ap[q];
            #pragma unroll
            for (int r = 0; r < 4; ++r) A[q * 4 + r] = -__expf(v[r]);
        }
    }
    const float Dd = Dp[d];
    float h[DSTATE];
    {
        size_t idx = (((size_t)b * CCH + c) * DINNER + d) * DSTATE;
        #pragma unroll
        for (int q = 0; q < 4; ++q) {
            f32x4 v = *(const f32x4*)(chunkH + idx + q * 4);
            #pragma unroll
            for (int r = 0; r < 4; ++r) h[q * 4 + r] = v[r];
        }
    }

    const float* dtp = dt + ((size_t)b * LL + l0) * DINNER + d;
    bf16* up = u + ((size_t)b * LL + l0) * DINNER + d;
    const float* bcp = BC + ((size_t)b * LL + l0) * 32;
    const bf16* zp = xz + ((size_t)b * LL + l0) * N_XZ + DINNER + d;

    #pragma unroll 2
    for (int i = 0; i < LCH; ++i) {
        float dtv = *dtp;
        float uv  = (float)*up;
        float du  = dtv * uv;
        f32x4 Bv[4], Cv[4];
        #pragma unroll
        for (int q = 0; q < 4; ++q) {
            Bv[q] = *(const f32x4*)(bcp + q * 4);
            Cv[q] = *(const f32x4*)(bcp + 16 + q * 4);
        }
        float acc = 0.f;
        #pragma unroll
        for (int n = 0; n < DSTATE; ++n) {
            float a = __expf(dtv * A[n]);
            h[n] = fmaf(a, h[n], du * Bv[n >> 2][n & 3]);
            acc = fmaf(h[n], Cv[n >> 2][n & 3], acc);
        }
        float zv = (float)*zp;
        acc = fmaf(Dd, uv, acc);
        acc *= zv / (1.f + __expf(-zv));
        *up = __float2bfloat16(acc);
        dtp += DINNER; up += DINNER; bcp += 32; zp += N_XZ;
    }
}

extern "C" void kernel_launch(void* const* d_in, const int* in_sizes, int n_in,
                              void* d_out, int out_size, void* d_ws, size_t ws_size,
                              hipStream_t stream) {
    const float* x         = (const float*)d_in[0];
    const float* in_proj_w = (const float*)d_in[1];
    const float* conv_w    = (const float*)d_in[2];
    const float* conv_b    = (const float*)d_in[3];
    const float* x_proj_w  = (const float*)d_in[4];
    const float* dt_proj_w = (const float*)d_in[5];
    const float* dt_proj_b = (const float*)d_in[6];
    const float* A_log     = (const float*)d_in[7];
    const float* Dp        = (const float*)d_in[8];
    const float* out_proj_w= (const float*)d_in[9];
    float* out = (float*)d_out;

    // workspace layout (~80.7 MB); xbf aliases dt; chunkP/H alias Wt1/Wt2
    char* p = (char*)d_ws;
    float* dt   = (float*)p;                          p += (size_t)MM * DINNER * 4;
    bf16*  xbf  = (bf16*)dt;
    bf16*  xz   = (bf16*)p;                           p += (size_t)MM * N_XZ * 2;
    bf16*  u    = (bf16*)p;                           p += (size_t)MM * DINNER * 2;
    bf16*  ssm  = (bf16*)p;                           p += (size_t)MM * N_SSM * 2;
    bf16*  Wt1  = (bf16*)p;                           p += (size_t)N_XZ * DMODEL * 2;      // 8 MB
    bf16*  Wt2  = (bf16*)p;                           p += (size_t)N_SSM_PAD * DINNER * 2; // 8.9 MB
    bf16*  Wt3  = (bf16*)p;                           p += (size_t)DINNER * DINNER * 2;
    bf16*  Wt4  = (bf16*)p;                           p += (size_t)DMODEL * DINNER * 2;
    float* BC   = (float*)p;                          p += (size_t)MM * 32 * 4;            // 256 KB
    float* chunkP = (float*)Wt1;   // B*CCH*DINNER*16 f32 = 8 MB exactly
    float* chunkH = (float*)Wt2;   // 8 MB of Wt2's 8.9

    // 0) fused prep: 4 transposes + x cvt in one launch
    prep_kernel<<<16448, 256, 0, stream>>>(x, xbf, in_proj_w, Wt1, x_proj_w, Wt2,
                                           dt_proj_w, Wt3, out_proj_w, Wt4);
    // 1) xz = xbf @ W1   (2048 x 4096, K=1024) — 1024 blocks, SWZ: 8 n-tiles/XCD
    mfma_gemm<0, 1, 3><<<dim3(N_XZ / TN, MM / TM), 256, 0, stream>>>(
        xbf, DMODEL, Wt1, DMODEL, nullptr, xz, N_XZ, nullptr, N_XZ, DMODEL);
    // 2) u = silu(conv(x_inner)+b)
    {
        int n = BB * LL * DINNER;
        conv_silu_kernel<<<(n + 255) / 256, 256, 0, stream>>>(xz, conv_w, conv_b, u);
    }
    // 3) ssm = u @ W2    (2048 x 2080, K=2048); cols<32 -> BC f32 — 544 blocks, no SWZ
    mfma_gemm<3><<<dim3(N_SSM_PAD / TN, MM / TM), 256, 0, stream>>>(
        u, DINNER, Wt2, DINNER, BC, ssm, N_SSM, nullptr, N_SSM, DINNER);
    // 4) dt = softplus(ssm[:,32:] @ W3 + b)  (2048 x 2048) — 512 blocks, SWZ: 4 n-tiles/XCD
    mfma_gemm<1, 1, 2><<<dim3(DINNER / TN, MM / TM), 256, 0, stream>>>(
        ssm + 2 * DSTATE, N_SSM, Wt3, DINNER, dt, nullptr, DINNER, dt_proj_b, DINNER, DINNER);
    // 5) chunked selective scan: A (local), P (prefix), B (apply; y over u)
    scan_phase_a<<<dim3(DINNER / 256, CCH, BB), 256, 0, stream>>>(dt, u, BC, A_log, chunkP, chunkH);
    scan_phase_p<<<dim3(BB * DINNER * DSTATE / 256), 256, 0, stream>>>(chunkP, chunkH);
    scan_phase_b<<<dim3(DINNER / 256, CCH, BB), 256, 0, stream>>>(dt, u, BC, xz, A_log, Dp, chunkH);
    // 6) out = y @ W4    (2048 x 1024, K=2048), split-K=2 atomic — 512 blocks, SWZ
    hipMemsetAsync(out, 0, (size_t)out_size * sizeof(float), stream);
    mfma_gemm<2, 2, 1><<<dim3(DMODEL / TN, MM / TM, 2), 256, 0, stream>>>(
        u, DINNER, Wt4, DINNER, out, nullptr, DMODEL, nullptr, DMODEL, DINNER);
}